// Round 4
// baseline (469.263 us; speedup 1.0000x reference)
//
#include <hip/hip_runtime.h>
#include <hip/hip_bf16.h>

typedef float f32x4 __attribute__((ext_vector_type(4)));
typedef __bf16 bf16x8 __attribute__((ext_vector_type(8)));
typedef __bf16 bf16x4 __attribute__((ext_vector_type(4)));
typedef unsigned int u32;
typedef const __attribute__((address_space(1))) u32* gas_u32;
typedef __attribute__((address_space(3))) u32* las_u32;

#define NPRE (45L * 384 * 128)   // elements per transposed weight array
#define X_TOT (32800L * 1025)    // total elements of x

__device__ float g_bias2[45 * 128];  // b_post + b_pre . w_post

// ---- prep (unchanged from passing v3b): LDS-transpose weights + bias fold ----
// wpreT[k][o][i'] = w_pre[k][perm(i')][o],  perm(i') = (i'&31)*4 + (i'>>5)
// wpostT[k][s][n'][pl] = w_post[k][d(s*128+pl)][perm(n')]
//   d(p) = (p&~31) + 16*(j>>2) + 4*q + (j&3), q=(p&31)>>3, j=(p&31)&7
__global__ __launch_bounds__(256) void prep_weights(
    const float* __restrict__ w_pre, const float* __restrict__ w_post,
    const float* __restrict__ b_pre, const float* __restrict__ b_post,
    __bf16* __restrict__ wpreT, __bf16* __restrict__ wpostT) {
  __shared__ float tile[128 * 65];
  const int tid = threadIdx.x;
  const int bid = blockIdx.x;
  if (bid < 270) {
    int k = bid / 6, o0 = (bid % 6) * 64;
#pragma unroll
    for (int it = 0; it < 32; ++it) {
      int i = it * 4 + (tid >> 6);
      tile[i * 65 + (tid & 63)] = w_pre[((long)(k * 128 + i)) * 384 + o0 + (tid & 63)];
    }
    __syncthreads();
#pragma unroll
    for (int it = 0; it < 8; ++it) {
      int lin = it * 256 + tid;
      int ol = lin >> 5;
      int ip0 = (lin & 31) * 4;
      bf16x4 v;
#pragma unroll
      for (int jj = 0; jj < 4; ++jj) {
        int ip = ip0 + jj;
        int irow = ((ip & 31) << 2) + (ip >> 5);
        v[jj] = (__bf16)tile[irow * 65 + ol];
      }
      *(bf16x4*)(wpreT + ((long)(k * 384 + o0 + ol)) * 128 + ip0) = v;
    }
  } else if (bid < 405) {
    int r = bid - 270;
    int k = r / 3, s = r % 3;
#pragma unroll
    for (int h = 0; h < 2; ++h) {
      if (h) __syncthreads();
#pragma unroll
      for (int it = 0; it < 32; ++it) {
        int dl = it * 2 + (tid >> 7);
        int i = tid & 127;
        tile[dl * 129 + i] = w_post[((long)(k * 384 + s * 128 + h * 64 + dl)) * 128 + i];
      }
      __syncthreads();
#pragma unroll
      for (int it = 0; it < 8; ++it) {
        int lin = it * 256 + tid;
        int np = lin >> 4;
        int pl0 = h * 64 + (lin & 15) * 4;
        int i_n = ((np & 31) << 2) + (np >> 5);
        int w0 = pl0 & 31, qq = w0 >> 3, j0 = w0 & 7;
        int dbase = (pl0 & ~31) - h * 64 + (qq << 2);
        bf16x4 v;
#pragma unroll
        for (int jj = 0; jj < 4; ++jj) {
          int j = j0 + jj;
          int dloc = dbase + ((j >> 2) << 4) + (j & 3);
          v[jj] = (__bf16)tile[dloc * 129 + i_n];
        }
        *(bf16x4*)(wpostT + (((long)(k * 3 + s)) * 128 + np) * 128 + pl0) = v;
      }
    }
  } else {
    int k = bid - 405;
    int n = tid;
    if (n < 128) {
      float acc = b_post[k * 128 + n];
      for (int d = 0; d < 384; ++d)
        acc += b_pre[k * 384 + d] * w_post[((long)k * 384 + d) * 128 + n];
      g_bias2[k * 128 + n] = acc;
    }
  }
}

// ---- band MLP v4: M=32/wave, 256 thr, counted-vmcnt prefetch-2 (T3+T4) ----
// Each weight ds_read feeds 2 MFMAs (row-halves h=0/1): weight-LDS traffic
// and bank conflicts halve vs v3b. 12 phases: 6 wpre halves (GEMM1) + 6
// wpost halves hf-major (GEMM2: hf=0 over all d -> mid-store -> hf=1).
// Buffer map buf(p) = (p+2)%3 lets stage(0) (buf2, not aliased by sA)
// overlap the whole x-stage prologue. Waits: vmcnt(4) (=stage(p+1) ops)
// -- always >= conservative even with mid-stores/spills (FIFO retire).
__global__ __launch_bounds__(256, 3) void band_mlp(
    const float* __restrict__ x,
    const __bf16* __restrict__ wpreT, const __bf16* __restrict__ wpostT,
    float* __restrict__ out) {
  __shared__ __bf16 sB[3 * 64 * 128];  // 48KB; sA (32KB) aliases bufs {0,1}
  __bf16* const sA = sB;

  const int tid = threadIdx.x;
  const int bid = blockIdx.x;

  int k, tile;
  if (bid < 2520) {
    int s = bid & 7, seq = bid >> 3;
    int bi = seq / 63;
    tile = seq - bi * 63;
    k = bi * 8 + s;
  } else {
    int r = bid - 2520;
    k = 40 + r / 63;
    tile = r - (k - 40) * 63;
  }

  const int f0 = (k <= 28) ? (k * (k + 7)) / 2 : 490 + 32 * (k - 28);
  int len = (4 + k < 32) ? 4 + k : 32;
  if (len > 1025 - f0) len = 1025 - f0;

  const __bf16* wpre_k  = wpreT  + (long)k * 384 * 128;
  const __bf16* wpost_k = wpostT + (long)k * 384 * 128;

  auto stage_half = [&](int p) {       // 16KB half-slab p -> sB[(p+2)%3]
    const __bf16* src;
    if (p < 6) {
      src = wpre_k + (long)p * 8192;
    } else {
      int pm = p - 6, hf = pm / 3, s2 = pm % 3;           // hf-major
      src = wpost_k + (long)s2 * 16384 + (long)hf * 8192;
    }
    __bf16* dst = sB + ((p + 2) % 3) * 8192;
#pragma unroll
    for (int u = 0; u < 4; ++u) {
      int lin = u * 256 + tid;         // 16B chunk id, wave-linear dest
      int row = lin >> 4, gp = lin & 15;
      int gl = gp ^ (row & 7);
      __builtin_amdgcn_global_load_lds((gas_u32)(const void*)(src + row * 128 + gl * 8),
                                       (las_u32)(void*)(dst + lin * 8), 16, 0, 0);
    }
  };

  stage_half(0);                       // buf2: disjoint from sA, overlaps prologue

  const int lane = tid & 63;
  const int wid = tid >> 6;            // 4 waves, 32 rows each
  const int l15 = lane & 15;
  const int q = lane >> 4;
  const int m0 = wid * 32;
  const int swz = l15 & 7;

  // bias prefetch (retires long before the loop's counted waits)
  float bp[8];
#pragma unroll
  for (int j = 0; j < 8; ++j) {
    int n = j * 16 + l15;
    bp[j] = g_bias2[k * 128 + ((n & 31) << 2) + (n >> 5)];
  }

  // ---- stage Xg tile: 128 rows, float4 loads (16 per thread), swizzled sA ----
  {
#pragma unroll
    for (int it = 0; it < 16; ++it) {
      int unit = it * 256 + tid;       // (row 128) x (c 4) x (l8 8)
      int row = unit >> 5, rem = unit & 31;
      int c = rem >> 3, l8 = rem & 7;
      int m = tile * 128 + row;
      int b = m / 1000, t = m - b * 1000;
      long gi = ((long)(b * 4 + c) * 1000 + t) * 1025 + f0 + l8 * 4;
      f32x4 v = (f32x4){0.f, 0.f, 0.f, 0.f};
      if (m < 8000) {
        if (l8 * 4 + 4 <= len && gi + 4 <= X_TOT) {
          v = *(const f32x4*)(x + gi);
        } else {
#pragma unroll
          for (int j = 0; j < 4; ++j)
            if (l8 * 4 + j < len && gi + j < X_TOT) v[j] = x[gi + j];
        }
      }
      int col0 = c * 32 + l8 * 4;
      int gr = (col0 >> 3) ^ (row & 7);
      bf16x4 bv;
#pragma unroll
      for (int j = 0; j < 4; ++j) bv[j] = (__bf16)v[j];
      *(bf16x4*)(sA + row * 128 + gr * 8 + (col0 & 7)) = bv;
    }
  }

  __syncthreads();                     // sA writes visible

  // hoist this wave's 32 rows of Xg: 32 VGPR, reused by all 6 GEMM1 phases
  bf16x8 xb[2][4];
#pragma unroll
  for (int h = 0; h < 2; ++h)
#pragma unroll
    for (int ch = 0; ch < 4; ++ch)
      xb[h][ch] = *(const bf16x8*)(sA + (m0 + h * 16 + l15) * 128 + (((ch * 4 + q) ^ swz) * 8));

  __syncthreads();                     // hoists done; sA region (bufs 0,1) free

  stage_half(1);                       // buf0 (pipeline now depth 2)

  bf16x8 hA[2][12];                    // H rows h*16.., 96 VGPR
  f32x4 accY[2][4];                    // one n-half at a time (hf-major)

  auto store_half = [&](int hf) {
#pragma unroll
    for (int h = 0; h < 2; ++h) {
#pragma unroll
      for (int r = 0; r < 4; ++r) {
        int m = tile * 128 + m0 + h * 16 + q * 4 + r;
        if (m < 8000) {
          int b = m / 1000, t = m - b * 1000;
          long ob = (long)(b * 4) * 1025000 + (long)t * 1025 + f0;
#pragma unroll
          for (int nt = 0; nt < 4; ++nt) {
            int n = hf * 64 + nt * 16 + l15;
            int w = n & 31, c = n >> 5;
            if (w < len)
              out[ob + (long)c * 1025000 + w] = accY[h][nt][r] + bp[hf * 4 + nt];
          }
        }
      }
    }
  };

#pragma unroll
  for (int p = 0; p < 12; ++p) {
    if (p == 11) asm volatile("s_waitcnt vmcnt(0) lgkmcnt(0)" ::: "memory");
    else         asm volatile("s_waitcnt vmcnt(4) lgkmcnt(0)" ::: "memory");
    __builtin_amdgcn_s_barrier();      // stage(p) landed; prior readers retired
    __builtin_amdgcn_sched_barrier(0);
    if (p < 10) stage_half(p + 2);
    const __bf16* buf = sB + ((p + 2) % 3) * 8192;
    if (p < 6) {
      // GEMM1: o-rows p*64..p*64+63, K=128; each wa feeds both row-halves
      f32x4 accH[2][4];
#pragma unroll
      for (int h = 0; h < 2; ++h)
#pragma unroll
        for (int ot = 0; ot < 4; ++ot) accH[h][ot] = (f32x4){0.f, 0.f, 0.f, 0.f};
#pragma unroll
      for (int ch = 0; ch < 4; ++ch) {
#pragma unroll
        for (int ot = 0; ot < 4; ++ot) {
          bf16x8 wa = *(const bf16x8*)(buf + (ot * 16 + l15) * 128 + (((ch * 4 + q) ^ swz) * 8));
          accH[0][ot] = __builtin_amdgcn_mfma_f32_16x16x32_bf16(wa, xb[0][ch], accH[0][ot], 0, 0, 0);
          accH[1][ot] = __builtin_amdgcn_mfma_f32_16x16x32_bf16(wa, xb[1][ch], accH[1][ot], 0, 0, 0);
        }
      }
      // pack: lane holds H[m0+h*16+l15][OT*16+q*4+r]
#pragma unroll
      for (int h = 0; h < 2; ++h)
#pragma unroll
        for (int ot = 0; ot < 4; ++ot) {
          int OT = p * 4 + ot;
#pragma unroll
          for (int r = 0; r < 4; ++r)
            hA[h][OT >> 1][(OT & 1) * 4 + r] = (__bf16)accH[h][ot][r];
        }
    } else {
      // GEMM2 (hf-major): n-half hf, d-slice s2; each wb feeds both halves
      const int pm = p - 6, hf = pm / 3, s2 = pm % 3;
      if (s2 == 0) {
#pragma unroll
        for (int h = 0; h < 2; ++h)
#pragma unroll
          for (int nt = 0; nt < 4; ++nt) accY[h][nt] = (f32x4){0.f, 0.f, 0.f, 0.f};
      }
#pragma unroll
      for (int cl = 0; cl < 4; ++cl) {
        int c = s2 * 4 + cl;
        bf16x8 a20 = hA[0][c], a21 = hA[1][c];
#pragma unroll
        for (int nt = 0; nt < 4; ++nt) {
          bf16x8 wb = *(const bf16x8*)(buf + (nt * 16 + l15) * 128 + (((cl * 4 + q) ^ swz) * 8));
          accY[0][nt] = __builtin_amdgcn_mfma_f32_16x16x32_bf16(a20, wb, accY[0][nt], 0, 0, 0);
          accY[1][nt] = __builtin_amdgcn_mfma_f32_16x16x32_bf16(a21, wb, accY[1][nt], 0, 0, 0);
        }
      }
      if (pm == 2) store_half(0);      // hf=0 done: store now, overlaps hf=1 phases
      (void)hf;
    }
  }

  store_half(1);                       // final epilogue: n-half 1

  // keep prep/bias values live against DCE paranoia (no-op)
}

extern "C" void kernel_launch(void* const* d_in, const int* in_sizes, int n_in,
                              void* d_out, int out_size, void* d_ws, size_t ws_size,
                              hipStream_t stream) {
  const float* x      = (const float*)d_in[0];
  const float* w_pre  = (const float*)d_in[1];
  const float* b_pre  = (const float*)d_in[2];
  const float* w_post = (const float*)d_in[3];
  const float* b_post = (const float*)d_in[4];
  float* out = (float*)d_out;

  __bf16* wpreT  = (__bf16*)d_ws;
  __bf16* wpostT = (__bf16*)((char*)d_ws + NPRE * 2);

  prep_weights<<<450, 256, 0, stream>>>(w_pre, w_post, b_pre, b_post, wpreT, wpostT);
  band_mlp<<<2835, 256, 0, stream>>>(x, wpreT, wpostT, out);
}

// Round 5
// 425.835 us; speedup vs baseline: 1.1020x; 1.1020x over previous
//
#include <hip/hip_runtime.h>
#include <hip/hip_bf16.h>

typedef float f32x4 __attribute__((ext_vector_type(4)));
typedef __bf16 bf16x8 __attribute__((ext_vector_type(8)));
typedef __bf16 bf16x4 __attribute__((ext_vector_type(4)));
typedef unsigned int u32;
typedef const __attribute__((address_space(1))) u32* gas_u32;
typedef __attribute__((address_space(3))) u32* las_u32;

#define NPRE (45L * 384 * 128)   // elements per transposed weight array
#define X_TOT (32800L * 1025)    // total elements of x

__device__ float g_bias2[45 * 128];  // b_post + b_pre . w_post

// ---- prep (unchanged, verified): LDS-transpose weights + bias fold ----
// wpreT[k][o][i'] = w_pre[k][perm(i')][o],  perm(i') = (i'&31)*4 + (i'>>5)
// wpostT[k][s][n'][pl] = w_post[k][d(s*128+pl)][perm(n')]
//   d(p) = (p&~31) + 16*(j>>2) + 4*q + (j&3), q=(p&31)>>3, j=(p&31)&7
__global__ __launch_bounds__(256) void prep_weights(
    const float* __restrict__ w_pre, const float* __restrict__ w_post,
    const float* __restrict__ b_pre, const float* __restrict__ b_post,
    __bf16* __restrict__ wpreT, __bf16* __restrict__ wpostT) {
  __shared__ float tile[128 * 65];
  const int tid = threadIdx.x;
  const int bid = blockIdx.x;
  if (bid < 270) {
    int k = bid / 6, o0 = (bid % 6) * 64;
#pragma unroll
    for (int it = 0; it < 32; ++it) {
      int i = it * 4 + (tid >> 6);
      tile[i * 65 + (tid & 63)] = w_pre[((long)(k * 128 + i)) * 384 + o0 + (tid & 63)];
    }
    __syncthreads();
#pragma unroll
    for (int it = 0; it < 8; ++it) {
      int lin = it * 256 + tid;
      int ol = lin >> 5;
      int ip0 = (lin & 31) * 4;
      bf16x4 v;
#pragma unroll
      for (int jj = 0; jj < 4; ++jj) {
        int ip = ip0 + jj;
        int irow = ((ip & 31) << 2) + (ip >> 5);
        v[jj] = (__bf16)tile[irow * 65 + ol];
      }
      *(bf16x4*)(wpreT + ((long)(k * 384 + o0 + ol)) * 128 + ip0) = v;
    }
  } else if (bid < 405) {
    int r = bid - 270;
    int k = r / 3, s = r % 3;
#pragma unroll
    for (int h = 0; h < 2; ++h) {
      if (h) __syncthreads();
#pragma unroll
      for (int it = 0; it < 32; ++it) {
        int dl = it * 2 + (tid >> 7);
        int i = tid & 127;
        tile[dl * 129 + i] = w_post[((long)(k * 384 + s * 128 + h * 64 + dl)) * 128 + i];
      }
      __syncthreads();
#pragma unroll
      for (int it = 0; it < 8; ++it) {
        int lin = it * 256 + tid;
        int np = lin >> 4;
        int pl0 = h * 64 + (lin & 15) * 4;
        int i_n = ((np & 31) << 2) + (np >> 5);
        int w0 = pl0 & 31, qq = w0 >> 3, j0 = w0 & 7;
        int dbase = (pl0 & ~31) - h * 64 + (qq << 2);
        bf16x4 v;
#pragma unroll
        for (int jj = 0; jj < 4; ++jj) {
          int j = j0 + jj;
          int dloc = dbase + ((j >> 2) << 4) + (j & 3);
          v[jj] = (__bf16)tile[dloc * 129 + i_n];
        }
        *(bf16x4*)(wpostT + (((long)(k * 3 + s)) * 128 + np) * 128 + pl0) = v;
      }
    }
  } else {
    int k = bid - 405;
    int n = tid;
    if (n < 128) {
      float acc = b_post[k * 128 + n];
      for (int d = 0; d < 384; ++d)
        acc += b_pre[k * 384 + d] * w_post[((long)k * 384 + d) * 128 + n];
      g_bias2[k * 128 + n] = acc;
    }
  }
}

// ---- band MLP v5: v3b structure + granule-major LDS + 24-phase / 32KB ----
// LDS layouts (16-B chunks):
//   sA  (128 rows x 16 K-granules): chunk(g,row) = g*128 + (row ^ (g&7))
//   slab (64 rows x  8 K-granules): chunk(g,row) = g*64  + (row ^ g)
// => every 16-lane fragment read is 256 contiguous (permuted) bytes: 2-way
//    bank aliasing only (free, m136). Stage writes are linear (DMA) with the
//    inverse permutation applied on the per-lane GLOBAL source address.
// 24 phases (12 GEMM1 (s,kh) + 12 GEMM2 (s2,hf,q2)), 8-KB quarter-slabs,
// 3-buffer rotation inside sA's 32 KB (sA dead after xb hoist), prefetch
// depth 2, counted vmcnt(1) (1 stage op/thread/phase). 32 KB LDS -> 4
// blocks/CU = 32 waves/CU. Stores only in the final epilogue (no vm ops in
// the loop; v4 lesson).
__global__ __launch_bounds__(512, 6) void band_mlp(
    const float* __restrict__ x,
    const __bf16* __restrict__ wpreT, const __bf16* __restrict__ wpostT,
    float* __restrict__ out) {
  __shared__ __bf16 sB[16 * 128 * 8];  // 32 KB; sA = whole thing; bufs = 3 x 4096 bf16
  __bf16* const sA = sB;

  const int tid = threadIdx.x;
  const int bid = blockIdx.x;

  int k, tile;
  if (bid < 2520) {
    int s = bid & 7, seq = bid >> 3;
    int bi = seq / 63;
    tile = seq - bi * 63;
    k = bi * 8 + s;
  } else {
    int r = bid - 2520;
    k = 40 + r / 63;
    tile = r - (k - 40) * 63;
  }

  const int f0 = (k <= 28) ? (k * (k + 7)) / 2 : 490 + 32 * (k - 28);
  int len = (4 + k < 32) ? 4 + k : 32;
  if (len > 1025 - f0) len = 1025 - f0;

  const __bf16* wpre_k  = wpreT  + (long)k * 384 * 128;
  const __bf16* wpost_k = wpostT + (long)k * 384 * 128;

  // 8-KB quarter-slab p -> sB[(p%3)*4096]; 1 chunk (16 B) per thread.
  // Phase decode: p<12: GEMM1 (s=p>>1, kh=p&1): rows o 64s.., K cols kh*64..
  //               p>=12: GEMM2 (pm=p-12: s2=pm>>2, hf=(pm>>1)&1, q2=pm&1)
  auto stage_q = [&](int p) {
    const __bf16* base;
    if (p < 12) {
      base = wpre_k + (long)((p >> 1) * 64) * 128 + (p & 1) * 64;
    } else {
      int pm = p - 12;
      base = wpost_k + (long)(((pm >> 2) * 128) + (((pm >> 1) & 1) * 64)) * 128 + (pm & 1) * 64;
    }
    int g = tid >> 6, rp = tid & 63;                 // phys chunk = tid
    const __bf16* src = base + (long)(rp ^ g) * 128 + g * 8;
    __builtin_amdgcn_global_load_lds((gas_u32)(const void*)src,
                                     (las_u32)(void*)(sB + (p % 3) * 4096 + tid * 8), 16, 0, 0);
  };

  // ---- stage Xg tile: 128 rows, float4 loads, granule-major swizzled sA ----
  {
#pragma unroll
    for (int it = 0; it < 8; ++it) {
      int unit = it * 512 + tid;       // (row 128) x (c 4) x (l8 8)
      int row = unit >> 5, rem = unit & 31;
      int c = rem >> 3, l8 = rem & 7;
      int m = tile * 128 + row;
      int b = m / 1000, t = m - b * 1000;
      long gi = ((long)(b * 4 + c) * 1000 + t) * 1025 + f0 + l8 * 4;
      f32x4 v = (f32x4){0.f, 0.f, 0.f, 0.f};
      if (m < 8000) {
        if (l8 * 4 + 4 <= len && gi + 4 <= X_TOT) {
          v = *(const f32x4*)(x + gi);
        } else {
#pragma unroll
          for (int j = 0; j < 4; ++j)
            if (l8 * 4 + j < len && gi + j < X_TOT) v[j] = x[gi + j];
        }
      }
      int col0 = c * 32 + l8 * 4;
      int g = col0 >> 3;               // K-granule 0..15
      bf16x4 bv;
#pragma unroll
      for (int j = 0; j < 4; ++j) bv[j] = (__bf16)v[j];
      *(bf16x4*)(sA + (g * 128 + (row ^ (g & 7))) * 8 + (col0 & 7)) = bv;
    }
  }

  const int lane = tid & 63;
  const int wid = tid >> 6;            // 8 waves, 16 rows each
  const int l15 = lane & 15;
  const int q = lane >> 4;
  const int m0 = wid * 16;

  __syncthreads();                     // sA writes visible (full drain)

  // hoist this wave's Xg fragments: 16 VGPR, reused by all GEMM1 phases
  bf16x8 xb[4];
#pragma unroll
  for (int ch = 0; ch < 4; ++ch) {
    int g = ch * 4 + q;
    xb[ch] = *(const bf16x8*)(sA + (g * 128 + ((m0 + l15) ^ (g & 7))) * 8);
  }

  __syncthreads();                     // all hoists retired; sA region is free

  stage_q(0);                          // fill pipeline: depth 2
  stage_q(1);

  bf16x8 hA[12];                       // H = GEMM2 A-frags, 48 VGPR
  f32x4 accY[8];                       // accY[0..3] doubles as GEMM1 accH

#pragma unroll
  for (int p = 0; p < 24; ++p) {
    if (p == 23) asm volatile("s_waitcnt vmcnt(0) lgkmcnt(0)" ::: "memory");
    else         asm volatile("s_waitcnt vmcnt(1) lgkmcnt(0)" ::: "memory");
    __builtin_amdgcn_s_barrier();      // stage(p) landed; prior readers retired
    __builtin_amdgcn_sched_barrier(0);
    if (p < 22) stage_q(p + 2);        // keep 2 quarter-slabs in flight
    const __bf16* buf = sB + (p % 3) * 4096;
    if (p < 12) {
      // GEMM1 quarter: o-rows (p>>1)*64.., K-half kh = p&1 (granules kh*8..)
      const int s = p >> 1, kh = p & 1;
      if (kh == 0) {
#pragma unroll
        for (int ot = 0; ot < 4; ++ot) accY[ot] = (f32x4){0.f, 0.f, 0.f, 0.f};
      }
#pragma unroll
      for (int cl = 0; cl < 2; ++cl) {
        int gl = cl * 4 + q;
        bf16x8 xv = xb[kh * 2 + cl];
#pragma unroll
        for (int ot = 0; ot < 4; ++ot) {
          bf16x8 wa = *(const bf16x8*)(buf + (gl * 64 + ((ot * 16 + l15) ^ gl)) * 8);
          accY[ot] = __builtin_amdgcn_mfma_f32_16x16x32_bf16(wa, xv, accY[ot], 0, 0, 0);
        }
      }
      if (kh == 1) {
        // pack: lane holds H[m0+l15][OT*16+q*4+r], OT = s*4+ot
#pragma unroll
        for (int ot = 0; ot < 4; ++ot) {
          int OT = s * 4 + ot;
#pragma unroll
          for (int r = 0; r < 4; ++r)
            hA[OT >> 1][(OT & 1) * 4 + r] = (__bf16)accY[ot][r];
        }
      }
    } else {
      // GEMM2 quarter: d-slice s2, n-half hf, d-half q2
      const int pm = p - 12, s2 = pm >> 2, hf = (pm >> 1) & 1, q2 = pm & 1;
      if (s2 == 0 && q2 == 0) {
#pragma unroll
        for (int nt = 0; nt < 4; ++nt) accY[hf * 4 + nt] = (f32x4){0.f, 0.f, 0.f, 0.f};
      }
#pragma unroll
      for (int cl = 0; cl < 2; ++cl) {
        int gl = cl * 4 + q;
        bf16x8 a2 = hA[s2 * 4 + q2 * 2 + cl];
#pragma unroll
        for (int nt = 0; nt < 4; ++nt) {
          bf16x8 wb = *(const bf16x8*)(buf + (gl * 64 + ((nt * 16 + l15) ^ gl)) * 8);
          accY[hf * 4 + nt] = __builtin_amdgcn_mfma_f32_16x16x32_bf16(a2, wb, accY[hf * 4 + nt], 0, 0, 0);
        }
      }
    }
  }

  // ---- epilogue: bias2 + scattered (64B-coalesced) stores, tail-guarded ----
  float bp[8];
#pragma unroll
  for (int nt = 0; nt < 8; ++nt) {
    int n = nt * 16 + l15;
    bp[nt] = g_bias2[k * 128 + ((n & 31) << 2) + (n >> 5)];
  }
  long obase[4];
  int mrow[4];
#pragma unroll
  for (int r = 0; r < 4; ++r) {
    int m = tile * 128 + m0 + q * 4 + r;
    mrow[r] = m;
    int b = m / 1000, t = m - b * 1000;
    obase[r] = (long)(b * 4) * 1025000 + (long)t * 1025 + f0;
  }
#pragma unroll
  for (int nt = 0; nt < 8; ++nt) {
    int n = nt * 16 + l15;
    int w = n & 31, c = n >> 5;
    if (w < len) {
#pragma unroll
      for (int r = 0; r < 4; ++r)
        if (mrow[r] < 8000)
          out[obase[r] + (long)c * 1025000 + w] = accY[nt][r] + bp[nt];
    }
  }
}

extern "C" void kernel_launch(void* const* d_in, const int* in_sizes, int n_in,
                              void* d_out, int out_size, void* d_ws, size_t ws_size,
                              hipStream_t stream) {
  const float* x      = (const float*)d_in[0];
  const float* w_pre  = (const float*)d_in[1];
  const float* b_pre  = (const float*)d_in[2];
  const float* w_post = (const float*)d_in[3];
  const float* b_post = (const float*)d_in[4];
  float* out = (float*)d_out;

  __bf16* wpreT  = (__bf16*)d_ws;
  __bf16* wpostT = (__bf16*)((char*)d_ws + NPRE * 2);

  prep_weights<<<450, 256, 0, stream>>>(w_pre, w_post, b_pre, b_post, wpreT, wpostT);
  band_mlp<<<2835, 512, 0, stream>>>(x, wpreT, wpostT, out);
}